// Round 3
// baseline (47.380 us; speedup 1.0000x reference)
//
#include <hip/hip_runtime.h>

// SpecAugment: time-warp (shift gather, W=80) + freq mask + time mask.
// B=128, M=80, T=3000 fp32. Memory-bound: ~217 MB actual traffic.
// R1: 37.66us (~5.8 TB/s). This round: skip time-mask-band loads +
// non-temporal load/store hints (native ext_vector_type for the builtin).

#define Bn 128
#define Mn 80
#define Tn 3000
#define Wn 80
#define TV (Tn / 4)  // 750 float4 per row; W%4==0 keeps shifted loads aligned

typedef float f32x4 __attribute__((ext_vector_type(4)));  // clang-native vec,
// required: __builtin_nontemporal_* rejects HIP's struct-based float4.

__global__ __launch_bounds__(256) void specaug_kernel(
    const float* __restrict__ spec,
    const int*   __restrict__ centers,
    const int*   __restrict__ p_fs, const int* __restrict__ p_fw,
    const int*   __restrict__ p_ts, const int* __restrict__ p_tw,
    float*       __restrict__ out)
{
    const int bm = blockIdx.x;            // one block per (b,m) row
    const int b  = bm / Mn;
    const int m  = bm - b * Mn;

    const int fs = *p_fs, fw = *p_fw, ts = *p_ts, tw = *p_tw;
    const int c  = centers[b];            // warp center for this sample

    const float* row  = spec + (size_t)bm * Tn;
    float*       orow = out  + (size_t)bm * Tn;

    const bool fmasked = (m >= fs) && (m < fs + fw);

    for (int v = threadIdx.x; v < TV; v += 256) {
        const int t4 = v * 4;
        f32x4 r;

        // fully time-masked vec4: no load needed
        const bool tmask_full = (t4 >= ts) && (t4 + 3 < ts + tw);

        if (fmasked || tmask_full) {
            r = 0.f;
        } else if (t4 + 3 < c) {
            // left region: idx = t - W. All-valid iff t4 >= W (W%4==0 makes
            // partial vectors impossible).
            if (t4 >= Wn) {
                r = __builtin_nontemporal_load(
                        reinterpret_cast<const f32x4*>(row + (t4 - Wn)));
            } else {
                r = 0.f;
            }
        } else if (t4 >= c) {
            // right region: idx = t + W. All-valid iff t4+3+W <= T-1.
            if (t4 <= Tn - Wn - 4) {
                r = __builtin_nontemporal_load(
                        reinterpret_cast<const f32x4*>(row + (t4 + Wn)));
            } else {
                r = 0.f;
            }
        } else {
            // the single vector straddling c: scalar gather with bounds check
            #pragma unroll
            for (int j = 0; j < 4; ++j) {
                const int t   = t4 + j;
                const int idx = (t < c) ? (t - Wn) : (t + Wn);
                r[j] = (idx >= 0 && idx < Tn) ? row[idx] : 0.f;
            }
        }

        if (!fmasked && !tmask_full) {
            // partial time-mask coverage (at most 2 vec4s per row)
            if (t4 + 3 >= ts && t4 < ts + tw) {
                #pragma unroll
                for (int j = 0; j < 4; ++j) {
                    const int t = t4 + j;
                    if (t >= ts && t < ts + tw) r[j] = 0.f;
                }
            }
        }

        __builtin_nontemporal_store(r, reinterpret_cast<f32x4*>(orow + t4));
    }
}

extern "C" void kernel_launch(void* const* d_in, const int* in_sizes, int n_in,
                              void* d_out, int out_size, void* d_ws, size_t ws_size,
                              hipStream_t stream) {
    const float* spec    = (const float*)d_in[0];
    const int*   centers = (const int*)d_in[1];
    const int*   p_fs    = (const int*)d_in[2];
    const int*   p_fw    = (const int*)d_in[3];
    const int*   p_ts    = (const int*)d_in[4];
    const int*   p_tw    = (const int*)d_in[5];
    float*       out     = (float*)d_out;

    specaug_kernel<<<dim3(Bn * Mn), dim3(256), 0, stream>>>(
        spec, centers, p_fs, p_fw, p_ts, p_tw, out);
}

// Round 4
// 38.221 us; speedup vs baseline: 1.2396x; 1.2396x over previous
//
#include <hip/hip_runtime.h>

// SpecAugment: time-warp (shift gather, W=80) + freq mask + time mask.
// B=128, M=80, T=3000 fp32. Memory-bound: ~215 MB actual traffic.
// R1: 37.66us (~5.8 TB/s), plain cached float4 streams.
// R2: nontemporal load/store -> 47.4us REGRESSION (nt bypass demotes the
//     store stream; normal cached path is faster on gfx950). Reverted.
// R3: R1 + skip loads for fully time-masked vec4s (-2 MB fetch).

#define Bn 128
#define Mn 80
#define Tn 3000
#define Wn 80
#define TV (Tn / 4)  // 750 float4 per row; W%4==0 keeps shifted loads aligned

__global__ __launch_bounds__(256) void specaug_kernel(
    const float* __restrict__ spec,
    const int*   __restrict__ centers,
    const int*   __restrict__ p_fs, const int* __restrict__ p_fw,
    const int*   __restrict__ p_ts, const int* __restrict__ p_tw,
    float*       __restrict__ out)
{
    const int bm = blockIdx.x;            // one block per (b,m) row
    const int b  = bm / Mn;
    const int m  = bm - b * Mn;

    const int fs = *p_fs, fw = *p_fw, ts = *p_ts, tw = *p_tw;
    const int c  = centers[b];            // warp center for this sample

    const float* row  = spec + (size_t)bm * Tn;
    float*       orow = out  + (size_t)bm * Tn;

    const bool fmasked = (m >= fs) && (m < fs + fw);

    for (int v = threadIdx.x; v < TV; v += 256) {
        const int t4 = v * 4;
        float r[4];

        // fully time-masked vec4: no load needed
        const bool tmask_full = (t4 >= ts) && (t4 + 3 < ts + tw);

        if (fmasked || tmask_full) {
            r[0] = r[1] = r[2] = r[3] = 0.f;
        } else if (t4 + 3 < c) {
            // left region: idx = t - W. All-valid iff t4 >= W (W%4==0 makes
            // partial vectors impossible).
            if (t4 >= Wn) {
                float4 v4 = *reinterpret_cast<const float4*>(row + (t4 - Wn));
                r[0] = v4.x; r[1] = v4.y; r[2] = v4.z; r[3] = v4.w;
            } else {
                r[0] = r[1] = r[2] = r[3] = 0.f;
            }
        } else if (t4 >= c) {
            // right region: idx = t + W. All-valid iff t4+3+W <= T-1.
            if (t4 <= Tn - Wn - 4) {
                float4 v4 = *reinterpret_cast<const float4*>(row + (t4 + Wn));
                r[0] = v4.x; r[1] = v4.y; r[2] = v4.z; r[3] = v4.w;
            } else {
                r[0] = r[1] = r[2] = r[3] = 0.f;
            }
        } else {
            // the single vector straddling c: scalar gather with bounds check
            #pragma unroll
            for (int j = 0; j < 4; ++j) {
                const int t   = t4 + j;
                const int idx = (t < c) ? (t - Wn) : (t + Wn);
                r[j] = (idx >= 0 && idx < Tn) ? row[idx] : 0.f;
            }
        }

        if (!fmasked && !tmask_full) {
            // partial time-mask coverage (at most 2 vec4s per row)
            if (t4 + 3 >= ts && t4 < ts + tw) {
                #pragma unroll
                for (int j = 0; j < 4; ++j) {
                    const int t = t4 + j;
                    if (t >= ts && t < ts + tw) r[j] = 0.f;
                }
            }
        }

        *reinterpret_cast<float4*>(orow + t4) = *reinterpret_cast<float4*>(r);
    }
}

extern "C" void kernel_launch(void* const* d_in, const int* in_sizes, int n_in,
                              void* d_out, int out_size, void* d_ws, size_t ws_size,
                              hipStream_t stream) {
    const float* spec    = (const float*)d_in[0];
    const int*   centers = (const int*)d_in[1];
    const int*   p_fs    = (const int*)d_in[2];
    const int*   p_fw    = (const int*)d_in[3];
    const int*   p_ts    = (const int*)d_in[4];
    const int*   p_tw    = (const int*)d_in[5];
    float*       out     = (float*)d_out;

    specaug_kernel<<<dim3(Bn * Mn), dim3(256), 0, stream>>>(
        spec, centers, p_fs, p_fw, p_ts, p_tw, out);
}

// Round 5
// 37.502 us; speedup vs baseline: 1.2634x; 1.0192x over previous
//
#include <hip/hip_runtime.h>

// SpecAugment: time-warp (shift gather, W=80) + freq mask + time mask.
// B=128, M=80, T=3000 fp32. Memory-bound: ~217 MB actual traffic.
// R1: 37.66us plain branchy vec4 loop (~5.8 TB/s eff).
// R2: nontemporal hints -> 47.4us REGRESSION (nt demotes store stream).
// R3: +load-skip in time-mask band -> 38.2us (neutral/noise).
// R4: region-split tight loops. Output row structure is exactly:
//     [80 zeros][row[0:c-80]][row[c+80:2920]][80 zeros]  (+masks)
//     -> branchless streaming loops per region; A/B test of branch overhead.

#define Bn 128
#define Mn 80
#define Tn 3000
#define Wn 80
#define TV (Tn / 4)          // 750 vec4 per row
#define VHEAD (Wn / 4)       // 20: head zeros
#define VTAIL ((Tn - Wn)/4)  // 730: tail zeros start

typedef float f32x4 __attribute__((ext_vector_type(4)));

__device__ __forceinline__ void tmask4(f32x4& r, int t4, int ts, unsigned tw) {
    #pragma unroll
    for (int j = 0; j < 4; ++j)
        if ((unsigned)(t4 + j - ts) < tw) r[j] = 0.f;
}

__global__ __launch_bounds__(256) void specaug_kernel(
    const float* __restrict__ spec,
    const int*   __restrict__ centers,
    const int*   __restrict__ p_fs, const int* __restrict__ p_fw,
    const int*   __restrict__ p_ts, const int* __restrict__ p_tw,
    float*       __restrict__ out)
{
    const int bm = blockIdx.x;            // one block per (b,m) row
    const int b  = bm / Mn;
    const int m  = bm - b * Mn;
    const int tid = threadIdx.x;

    const int fs = *p_fs, fw = *p_fw, ts = *p_ts;
    const unsigned tw = (unsigned)*p_tw;
    const int c  = centers[b];            // warp center, in [80, 2920)

    const float* row  = spec + (size_t)bm * Tn;
    float*       orow = out  + (size_t)bm * Tn;

    const f32x4 zero = {0.f, 0.f, 0.f, 0.f};

    // freq-masked row: pure zero-fill
    if (m >= fs && m < fs + fw) {
        for (int v = tid; v < TV; v += 256)
            *reinterpret_cast<f32x4*>(orow + v * 4) = zero;
        return;
    }

    const int vs  = c >> 2;               // vec containing c (20..729)
    const int rem = c & 3;
    const int vR  = vs + (rem ? 1 : 0);   // first full-right vec

    // head zeros [0,20) and tail zeros [730,750): one partial iter each
    if (tid < VHEAD)
        *reinterpret_cast<f32x4*>(orow + tid * 4) = zero;
    if (tid < TV - VTAIL)
        *reinterpret_cast<f32x4*>(orow + (VTAIL + tid) * 4) = zero;

    // left stream: v in [20, vs), reads row[t4-80]
    for (int v = VHEAD + tid; v < vs; v += 256) {
        const int t4 = v * 4;
        f32x4 r = *reinterpret_cast<const f32x4*>(row + (t4 - Wn));
        tmask4(r, t4, ts, tw);
        *reinterpret_cast<f32x4*>(orow + t4) = r;
    }

    // straddle vec (only if c not multiple of 4): lane 0 scalar gather
    if (rem && tid == 0) {
        const int t4 = vs * 4;
        f32x4 r;
        #pragma unroll
        for (int j = 0; j < 4; ++j) {
            const int t = t4 + j;
            r[j] = (t < c) ? row[t - Wn] : row[t + Wn];
        }
        tmask4(r, t4, ts, tw);
        *reinterpret_cast<f32x4*>(orow + t4) = r;
    }

    // right stream: v in [vR, 730), reads row[t4+80]
    for (int v = vR + tid; v < VTAIL; v += 256) {
        const int t4 = v * 4;
        f32x4 r = *reinterpret_cast<const f32x4*>(row + (t4 + Wn));
        tmask4(r, t4, ts, tw);
        *reinterpret_cast<f32x4*>(orow + t4) = r;
    }
}

extern "C" void kernel_launch(void* const* d_in, const int* in_sizes, int n_in,
                              void* d_out, int out_size, void* d_ws, size_t ws_size,
                              hipStream_t stream) {
    const float* spec    = (const float*)d_in[0];
    const int*   centers = (const int*)d_in[1];
    const int*   p_fs    = (const int*)d_in[2];
    const int*   p_fw    = (const int*)d_in[3];
    const int*   p_ts    = (const int*)d_in[4];
    const int*   p_tw    = (const int*)d_in[5];
    float*       out     = (float*)d_out;

    specaug_kernel<<<dim3(Bn * Mn), dim3(256), 0, stream>>>(
        spec, centers, p_fs, p_fw, p_ts, p_tw, out);
}

// Round 6
// 36.184 us; speedup vs baseline: 1.3094x; 1.0364x over previous
//
#include <hip/hip_runtime.h>

// SpecAugment: time-warp (shift gather, W=80) + freq mask + time mask.
// B=128, M=80, T=3000 fp32. Memory-bound: ~217 MB actual traffic.
// R1: 37.66us branchy vec4 loop (~5.8 TB/s eff).
// R2: nontemporal hints -> 47.4us REGRESSION (nt demotes store stream).
// R3: +load-skip in mask band -> 38.2us (neutral).
// R4: region-split branchless loops -> 37.5us (neutral; not branch-bound).
// R5: flat 1-vec4-per-thread grid (3750x256), no loops — tests whether
//     block/loop granularity & tail imbalance explain the last ~8%.

#define Bn 128
#define Mn 80
#define Tn 3000
#define Wn 80
#define TV (Tn / 4)  // 750 vec4 per row
#define NV (Bn * Mn * TV)  // 960000 total vec4s

typedef float f32x4 __attribute__((ext_vector_type(4)));

__global__ __launch_bounds__(256) void specaug_kernel(
    const float* __restrict__ spec,
    const int*   __restrict__ centers,
    const int*   __restrict__ p_fs, const int* __restrict__ p_fw,
    const int*   __restrict__ p_ts, const int* __restrict__ p_tw,
    float*       __restrict__ out)
{
    const int g  = blockIdx.x * 256 + threadIdx.x;   // global vec4 index
    const int bm = g / TV;                            // magic-mul division
    const int v  = g - bm * TV;
    const int b  = bm / Mn;
    const int m  = bm - b * Mn;

    const int fs = *p_fs, fw = *p_fw, ts = *p_ts;
    const unsigned tw = (unsigned)*p_tw;
    const int c  = centers[b];

    const float* row = spec + (size_t)bm * Tn;
    const int t4 = v * 4;
    f32x4 r;

    if ((m >= fs) && (m < fs + fw)) {
        r = 0.f;                                      // freq-masked row
    } else if (t4 + 3 < c) {
        // left region: idx = t - W; all-valid iff t4 >= W (W%4==0)
        if (t4 >= Wn) {
            r = *reinterpret_cast<const f32x4*>(row + (t4 - Wn));
        } else {
            r = 0.f;
        }
    } else if (t4 >= c) {
        // right region: idx = t + W; all-valid iff t4+3+W <= T-1
        if (t4 <= Tn - Wn - 4) {
            r = *reinterpret_cast<const f32x4*>(row + (t4 + Wn));
        } else {
            r = 0.f;
        }
    } else {
        // the single vec4 straddling c: scalar gather (always in-bounds:
        // c in [80,2920) so t-W >= 0 and t+W <= 2999 here)
        #pragma unroll
        for (int j = 0; j < 4; ++j) {
            const int t = t4 + j;
            r[j] = (t < c) ? row[t - Wn] : row[t + Wn];
        }
    }

    // time mask (branchless range test)
    #pragma unroll
    for (int j = 0; j < 4; ++j)
        if ((unsigned)(t4 + j - ts) < tw) r[j] = 0.f;

    *reinterpret_cast<f32x4*>(out + (size_t)bm * Tn + t4) = r;
}

extern "C" void kernel_launch(void* const* d_in, const int* in_sizes, int n_in,
                              void* d_out, int out_size, void* d_ws, size_t ws_size,
                              hipStream_t stream) {
    const float* spec    = (const float*)d_in[0];
    const int*   centers = (const int*)d_in[1];
    const int*   p_fs    = (const int*)d_in[2];
    const int*   p_fw    = (const int*)d_in[3];
    const int*   p_ts    = (const int*)d_in[4];
    const int*   p_tw    = (const int*)d_in[5];
    float*       out     = (float*)d_out;

    specaug_kernel<<<dim3(NV / 256), dim3(256), 0, stream>>>(
        spec, centers, p_fs, p_fw, p_ts, p_tw, out);
}